// Round 10
// baseline (650.671 us; speedup 1.0000x reference)
//
#include <hip/hip_runtime.h>
#include <hip/hip_bf16.h>
#include <math.h>

#define B_DIM 2048
#define L_DIM 2048
#define F_DIM 1024
#define H_DIM 4096
#define P_DIM 88

typedef unsigned short u16;
typedef short bf16x8 __attribute__((ext_vector_type(8)));
typedef float f32x4 __attribute__((ext_vector_type(4)));

// ---- bf16 split helpers (RNE) ----
__device__ __forceinline__ u16 f2bf(float x) {
    unsigned u = __float_as_uint(x);
    return (u16)((u + 0x7fffu + ((u >> 16) & 1u)) >> 16);
}
__device__ __forceinline__ float bf2f(u16 h) {
    return __uint_as_float(((unsigned)h) << 16);
}

// ---- async global->LDS, 16B per lane (dest = wave-uniform base + lane*16) ----
__device__ __forceinline__ void gload_lds16(const void* g, void* l) {
    unsigned loff = (unsigned)(uintptr_t)l;
    __builtin_amdgcn_global_load_lds(
        reinterpret_cast<const __attribute__((address_space(1))) void*>(
            reinterpret_cast<uintptr_t>(g)),
        reinterpret_cast<__attribute__((address_space(3))) void*>(loff),
        16, 0, 0);
}

// ---------------------------------------------------------------------------
// Fused start_fc + real-pair FFT: rows (2b, 2b+1) as re+im of ONE complex
// 2048-pt FFT; unpack via conjugate symmetry. Writes A1 [rh | rl | ih | il].
// ---------------------------------------------------------------------------
__global__ __launch_bounds__(256) void fft_kernel(
    const float* __restrict__ x, const float* __restrict__ w_start,
    const float* __restrict__ b_start, u16* __restrict__ A1)
{
    __shared__ float re[2048];
    __shared__ float im[2048];
    __shared__ float twr[1024];
    __shared__ float twi[1024];
    int b = blockIdx.x;                       // pair index 0..1023
    const size_t row0 = (size_t)(2 * b) * 2048;

    const float4* wp = (const float4*)w_start;
    float4 w0 = wp[0], w1 = wp[1], w2 = wp[2], w3 = wp[3];
    float bs = b_start[0];

    for (int i = threadIdx.x; i < 1024; i += 256) {
        float ang = -6.283185307179586f * ((float)i / 2048.0f);
        sincosf(ang, &twi[i], &twr[i]);
    }

    for (int l = threadIdx.x; l < 2048; l += 256) {
        const float4* xp0 = (const float4*)(x + (row0 + l) * 16);
        const float4* xp1 = (const float4*)(x + (row0 + 2048 + l) * 16);
        float4 a0 = xp0[0], a1 = xp0[1], a2 = xp0[2], a3 = xp0[3];
        float4 c0 = xp1[0], c1 = xp1[1], c2 = xp1[2], c3 = xp1[3];
        float va = bs, vb = bs;
        va += a0.x * w0.x + a0.y * w0.y + a0.z * w0.z + a0.w * w0.w;
        va += a1.x * w1.x + a1.y * w1.y + a1.z * w1.z + a1.w * w1.w;
        va += a2.x * w2.x + a2.y * w2.y + a2.z * w2.z + a2.w * w2.w;
        va += a3.x * w3.x + a3.y * w3.y + a3.z * w3.z + a3.w * w3.w;
        vb += c0.x * w0.x + c0.y * w0.y + c0.z * w0.z + c0.w * w0.w;
        vb += c1.x * w1.x + c1.y * w1.y + c1.z * w1.z + c1.w * w1.w;
        vb += c2.x * w2.x + c2.y * w2.y + c2.z * w2.z + c2.w * w2.w;
        vb += c3.x * w3.x + c3.y * w3.y + c3.z * w3.z + c3.w * w3.w;
        unsigned j = __brev((unsigned)l) >> 21;   // bit-reversed position
        re[j] = va;
        im[j] = vb;
    }
    __syncthreads();

    for (int s = 1; s <= 11; s++) {
        int half = 1 << (s - 1);
        for (int t = threadIdx.x; t < 1024; t += 256) {
            int j = t & (half - 1);
            int base = (t >> (s - 1)) << s;
            int idx = j << (11 - s);
            float wr = twr[idx], wi = twi[idx];
            int i0 = base + j, i1 = i0 + half;
            float br = re[i1], bi = im[i1];
            float tr = br * wr - bi * wi;
            float ti = br * wi + bi * wr;
            float ar = re[i0], ai = im[i0];
            re[i0] = ar + tr; im[i0] = ai + ti;
            re[i1] = ar - tr; im[i1] = ai - ti;
        }
        __syncthreads();
    }

    // unpack: A[k] = (Z[k]+conj(Z[N-k]))/2 ; B[k] = (Z[k]-conj(Z[N-k]))/(2i)
    const float sc = 0.5f * 0.022097086912079612f;  // 0.5 / sqrt(2048)
    u16* r0 = A1 + (size_t)(2 * b) * 4096;
    u16* r1 = r0 + 4096;
    for (int t = threadIdx.x; t < 1024; t += 256) {
        int k = t + 1;
        int nk = 2048 - k;
        float Zr = re[k], Zi = im[k], Yr = re[nk], Yi = im[nk];
        float Ar = (Zr + Yr) * sc;
        float Ai = (Zi - Yi) * sc;
        float Br = (Zi + Yi) * sc;
        float Bi = (Yr - Zr) * sc;
        u16 h, lo;
        h = f2bf(Ar); lo = f2bf(Ar - bf2f(h)); r0[t] = h; r0[1024 + t] = lo;
        h = f2bf(Ai); lo = f2bf(Ai - bf2f(h)); r0[2048 + t] = h; r0[3072 + t] = lo;
        h = f2bf(Br); lo = f2bf(Br - bf2f(h)); r1[t] = h; r1[1024 + t] = lo;
        h = f2bf(Bi); lo = f2bf(Bi - bf2f(h)); r1[2048 + t] = h; r1[3072 + t] = lo;
    }
}

// ---------------------------------------------------------------------------
// Weight conversion w[2][Kc][Nh] fp32 -> BTk, K-chunk-major:
// 16B unit index (c8, nrow) = c8 * N2 + nrow; N2 = 2*Nh; c8 = (seg*Kc+k)>>3.
// Row nrow=n (<Nh, real-out): segs {wrh, wrl, -wih, -wil}
// Row nrow=Nh+n (imag-out):   segs {wih, wil,  wrh,  wrl}
// ---------------------------------------------------------------------------
__global__ __launch_bounds__(256) void conv_bt_kernel(
    const float* __restrict__ w, u16* __restrict__ BTk, int Kc, int Nh)
{
    __shared__ float t0[32][33];
    __shared__ float t1[32][33];
    int k0 = blockIdx.x * 32, n0 = blockIdx.y * 32;
    int tx = threadIdx.x, ty = threadIdx.y;     // (32, 8)
    const float* w0 = w;
    const float* w1 = w + (size_t)Kc * Nh;

#pragma unroll
    for (int i = 0; i < 4; i++) {
        int k = k0 + ty + 8 * i;
        t0[ty + 8 * i][tx] = w0[(size_t)k * Nh + n0 + tx];
        t1[ty + 8 * i][tx] = w1[(size_t)k * Nh + n0 + tx];
    }
    __syncthreads();

    const size_t N2 = 2 * (size_t)Nh;
    int k = k0 + tx;
    int ke = k & 7;
#pragma unroll
    for (int i = 0; i < 4; i++) {
        int nl = ty + 8 * i;
        int n = n0 + nl;
        float br = t0[tx][nl];
        float bi = t1[tx][nl];
        u16 brh = f2bf(br); u16 brl = f2bf(br - bf2f(brh));
        float nbi = -bi;
        u16 nih = f2bf(nbi); u16 nil = f2bf(nbi - bf2f(nih));
        u16 pih = f2bf(bi);  u16 pil = f2bf(bi - bf2f(pih));
        // seg*Kc + k >> 3  (Kc multiple of 8 -> seg offset in c8 = seg*Kc/8)
        size_t c8b = (size_t)(k >> 3);
        size_t cstep = (size_t)(Kc >> 3);
        size_t ur = 0, ui = 0;
        // real-out row n
        ur = (c8b + 0 * cstep) * N2 + n;
        BTk[ur * 8 + ke] = brh;
        BTk[(c8b + 1 * cstep) * N2 * 8 + (size_t)n * 8 + ke] = brl;
        BTk[(c8b + 2 * cstep) * N2 * 8 + (size_t)n * 8 + ke] = nih;
        BTk[(c8b + 3 * cstep) * N2 * 8 + (size_t)n * 8 + ke] = nil;
        BTk[ur * 8 + ke] = brh;  // (redundant-safe; keeps first write explicit)
        // imag-out row Nh+n
        size_t nr = (size_t)(Nh + n);
        BTk[(c8b + 0 * cstep) * N2 * 8 + nr * 8 + ke] = pih;
        BTk[(c8b + 1 * cstep) * N2 * 8 + nr * 8 + ke] = pil;
        BTk[(c8b + 2 * cstep) * N2 * 8 + nr * 8 + ke] = brh;
        BTk[(c8b + 3 * cstep) * N2 * 8 + nr * 8 + ke] = brl;
        (void)ui;
    }
}

// ---------------------------------------------------------------------------
// Split-bf16 GEMM: R9 schedule + reg-staged B (B never touches LDS).
// 256x256 tile, BK=32, 8 waves (2M x 4N), ring of 4 LDS slots for A only.
// Per tile t: issue Bload(t+1)->regs [4]; stageA(t+2) [2]; preread ph2-A;
//   MFMA ph1(a,Bc); vmcnt(2|0); barrier; preread a(t+1); MFMA ph2(c,Bc).
// vmcnt(2): confirms A(t+1)+B(t+1) (oldest 6 of 8), leaves A(t+2) in flight.
// Loop unrolled x2 for static B-register ping-pong (nt is even).
// SWZ=1: layer-1 XCD grid. SWZ=2: layer-2 XCD-pinned A-panels + split-K.
// ---------------------------------------------------------------------------
extern __shared__ char smem8p[];

#define MFMA16X(ACC0, ACC1, ACC2, ACC3, A0, A1, A2, A3, B0, B1, B2, B3)          \
    ACC0[0] = __builtin_amdgcn_mfma_f32_16x16x32_bf16(A0, B0, ACC0[0], 0, 0, 0); \
    ACC0[1] = __builtin_amdgcn_mfma_f32_16x16x32_bf16(A0, B1, ACC0[1], 0, 0, 0); \
    ACC0[2] = __builtin_amdgcn_mfma_f32_16x16x32_bf16(A0, B2, ACC0[2], 0, 0, 0); \
    ACC0[3] = __builtin_amdgcn_mfma_f32_16x16x32_bf16(A0, B3, ACC0[3], 0, 0, 0); \
    ACC1[0] = __builtin_amdgcn_mfma_f32_16x16x32_bf16(A1, B0, ACC1[0], 0, 0, 0); \
    ACC1[1] = __builtin_amdgcn_mfma_f32_16x16x32_bf16(A1, B1, ACC1[1], 0, 0, 0); \
    ACC1[2] = __builtin_amdgcn_mfma_f32_16x16x32_bf16(A1, B2, ACC1[2], 0, 0, 0); \
    ACC1[3] = __builtin_amdgcn_mfma_f32_16x16x32_bf16(A1, B3, ACC1[3], 0, 0, 0); \
    ACC2[0] = __builtin_amdgcn_mfma_f32_16x16x32_bf16(A2, B0, ACC2[0], 0, 0, 0); \
    ACC2[1] = __builtin_amdgcn_mfma_f32_16x16x32_bf16(A2, B1, ACC2[1], 0, 0, 0); \
    ACC2[2] = __builtin_amdgcn_mfma_f32_16x16x32_bf16(A2, B2, ACC2[2], 0, 0, 0); \
    ACC2[3] = __builtin_amdgcn_mfma_f32_16x16x32_bf16(A2, B3, ACC2[3], 0, 0, 0); \
    ACC3[0] = __builtin_amdgcn_mfma_f32_16x16x32_bf16(A3, B0, ACC3[0], 0, 0, 0); \
    ACC3[1] = __builtin_amdgcn_mfma_f32_16x16x32_bf16(A3, B1, ACC3[1], 0, 0, 0); \
    ACC3[2] = __builtin_amdgcn_mfma_f32_16x16x32_bf16(A3, B2, ACC3[2], 0, 0, 0); \
    ACC3[3] = __builtin_amdgcn_mfma_f32_16x16x32_bf16(A3, B3, ACC3[3], 0, 0, 0);

// one tile body: BC* = current-tile B regs; BN* = next-tile B regs (loaded here)
#define GTILE(T, BC0, BC1, BC2, BC3, BN0, BN1, BN2, BN3)                          \
    {                                                                             \
        const bool haveStage = ((T) + 2 < te);                                    \
        const bool haveNext  = ((T) + 1 < te);                                    \
        if (haveNext) {                                                           \
            size_t u = (size_t)(unsigned)(colB((T) + 1) >> 3) * N2 + laneB;       \
            BN0 = BK[u];      BN1 = BK[u + 16];                                   \
            BN2 = BK[u + 32]; BN3 = BK[u + 48];                                   \
        }                                                                         \
        if (haveStage) stageA((T) + 2);                                           \
        const char* aS = aBase(T);                                                \
        bf16x8 c0 = *(const bf16x8*)(aS + 4096 + 0 * 1024);                       \
        bf16x8 c1 = *(const bf16x8*)(aS + 4096 + 1 * 1024);                       \
        bf16x8 c2 = *(const bf16x8*)(aS + 4096 + 2 * 1024);                       \
        bf16x8 c3 = *(const bf16x8*)(aS + 4096 + 3 * 1024);                       \
        __builtin_amdgcn_s_setprio(1);                                            \
        MFMA16X(acc[0], acc[1], acc[2], acc[3], a0, a1, a2, a3,                   \
                BC0, BC1, BC2, BC3)                                               \
        __builtin_amdgcn_s_setprio(0);                                            \
        if (haveStage) asm volatile("s_waitcnt vmcnt(2)" ::: "memory");           \
        else           asm volatile("s_waitcnt vmcnt(0)" ::: "memory");           \
        asm volatile("s_barrier" ::: "memory");                                   \
        if (haveNext) {                                                           \
            const char* aN = aBase((T) + 1);                                      \
            a0 = *(const bf16x8*)(aN + 0 * 1024);                                 \
            a1 = *(const bf16x8*)(aN + 1 * 1024);                                 \
            a2 = *(const bf16x8*)(aN + 2 * 1024);                                 \
            a3 = *(const bf16x8*)(aN + 3 * 1024);                                 \
        }                                                                         \
        __builtin_amdgcn_s_setprio(1);                                            \
        MFMA16X(acc[4], acc[5], acc[6], acc[7], c0, c1, c2, c3,                   \
                BC0, BC1, BC2, BC3)                                               \
        __builtin_amdgcn_s_setprio(0);                                            \
    }

template <int EPI, int SWZ>
__global__ __launch_bounds__(512, 2) void gemm8p(
    const u16* __restrict__ A, const u16* __restrict__ B,
    const float* __restrict__ biasL, const float* __restrict__ biasR,
    u16* __restrict__ OutU, float* __restrict__ P01, float* __restrict__ P23,
    int Kc, int KcLog, int NH, int nt)
{
    char* ldsA = smem8p;              // 4 slots x 16384 B  (A tile 256x32 bf16)

    const int tid = threadIdx.x;
    const int w = tid >> 6, lane = tid & 63;
    const int wr = w >> 2, wc = w & 3;           // 2M x 4N waves
    const int fr = lane & 15, kb = lane >> 4;

    int bx, by, z;
    if (SWZ == 1) {
        int b = blockIdx.x;
        int xcd = b & 7, idx = b >> 3;
        bx = 4 * xcd + (idx & 3);                // 32 N-blocks
        by = idx >> 2;                           // 8 M-blocks
        z = 0;
    } else if (SWZ == 2) {
        int b = blockIdx.x;                      // 64*ZK blocks, 1-D
        by = b & 7;                              // XCD-pinned A-panel
        int s = b >> 3;
        bx = s & 7;
        z = s >> 3;
    } else {
        bx = blockIdx.x; by = blockIdx.y; z = blockIdx.z;
    }
    const int n0 = bx * 256, m0 = by * 256;
    const size_t K4 = 4 * (size_t)Kc;
    const size_t N2 = 2 * (size_t)NH;            // BTk row width in 16B units

    // A staging: thread covers one 16B chunk per issue; 2 issues per tile
    const int srow = tid >> 2;
    const int lk8 = (((tid & 3) ^ ((tid >> 3) & 3))) * 8;   // src elem offset
    const int wb = (tid >> 6) * 1024;                       // wave dest base (B)

    // A frag read lane offset (bytes): row fr, chunk kb ^ ((fr>>1)&3)
    const int laneOff = fr * 64 + ((kb ^ ((fr >> 1) & 3)) << 4);

    // B reg-load: unit index = c8*N2 + nrow; per-lane constant part:
    const bf16x8* BK = (const bf16x8*)B;
    const size_t laneB = (size_t)kb * N2 + (size_t)(n0 + wc * 64 + fr);

    f32x4 acc[8][4];
#pragma unroll
    for (int i = 0; i < 8; i++)
#pragma unroll
        for (int j = 0; j < 4; j++)
            acc[i][j] = (f32x4){0.f, 0.f, 0.f, 0.f};

    const int t0 = z * nt, te = t0 + nt;

    auto colA = [&](int t) {
        int k0 = t << 5;
        int seg = k0 >> KcLog, kk = k0 & (Kc - 1);
        int r3 = seg >= 3 ? seg - 3 : seg;
        int bs = seg >= 3 ? 2 : 0;
        return (bs + (r3 == 1 ? 1 : 0)) * Kc + kk;
    };
    auto colB = [&](int t) {
        int k0 = t << 5;
        int seg = k0 >> KcLog, kk = k0 & (Kc - 1);
        int r3 = seg >= 3 ? seg - 3 : seg;
        int bs = seg >= 3 ? 2 : 0;
        return (bs + (r3 == 2 ? 1 : 0)) * Kc + kk;
    };
    auto stageA = [&](int t) {
        const u16* src = A + (size_t)(m0 + srow) * K4 + colA(t) + lk8;
        char* dst = ldsA + (t & 3) * 16384 + wb;
        gload_lds16(src, dst);
        gload_lds16(src + (size_t)128 * K4, dst + 8192);
    };
    auto aBase = [&](int t) -> const char* {
        return ldsA + (t & 3) * 16384 + wr * 8192 + laneOff;
    };

    // prologue: B(t0)->bc regs; stage A(t0), A(t0+1); confirm B(t0)+A(t0)
    bf16x8 bc0, bc1, bc2, bc3, bn0, bn1, bn2, bn3;
    {
        size_t u = (size_t)(unsigned)(colB(t0) >> 3) * N2 + laneB;
        bc0 = BK[u];      bc1 = BK[u + 16];
        bc2 = BK[u + 32]; bc3 = BK[u + 48];
    }
    stageA(t0);
    stageA(t0 + 1);
    asm volatile("s_waitcnt vmcnt(2)" ::: "memory");   // leaves A(t0+1)
    asm volatile("s_barrier" ::: "memory");

    bf16x8 a0, a1, a2, a3;
    {
        const char* aS = aBase(t0);
        a0 = *(const bf16x8*)(aS + 0 * 1024);
        a1 = *(const bf16x8*)(aS + 1 * 1024);
        a2 = *(const bf16x8*)(aS + 2 * 1024);
        a3 = *(const bf16x8*)(aS + 3 * 1024);
    }

    // main loop, unrolled x2 (nt even) for static B-reg ping-pong
    for (int t = t0; t < te; t += 2) {
        GTILE(t,     bc0, bc1, bc2, bc3, bn0, bn1, bn2, bn3)
        GTILE(t + 1, bn0, bn1, bn2, bn3, bc0, bc1, bc2, bc3)
    }

    // ---- epilogue ----
    const int fq = kb;
#pragma unroll
    for (int nj = 0; nj < 4; nj++) {
        int n = n0 + wc * 64 + nj * 16 + fr;
        if (EPI == 0) {
            bool left = (n < NH);
            int nn = left ? n : (n - NH);
            float bias = left ? biasL[n] : biasR[nn];
#pragma unroll
            for (int mi = 0; mi < 8; mi++) {
                int mb = m0 + wr * 128 + mi * 16 + fq * 4;
#pragma unroll
                for (int r = 0; r < 4; r++) {
                    float val = fmaxf(acc[mi][nj][r] + bias, 0.f);
                    u16 h = f2bf(val);
                    u16 lo = f2bf(val - bf2f(h));
                    size_t rb = (size_t)(mb + r) * (4 * (size_t)NH);
                    if (left) { OutU[rb + nn] = h; OutU[rb + NH + nn] = lo; }
                    else { OutU[rb + 2 * (size_t)NH + nn] = h; OutU[rb + 3 * (size_t)NH + nn] = lo; }
                }
            }
        } else {
            const size_t PSZ = (size_t)2048 * 2048;
            float* Out = (z < 2) ? (P01 + (size_t)z * PSZ) : (P23 + (size_t)(z - 2) * PSZ);
#pragma unroll
            for (int mi = 0; mi < 8; mi++) {
                int mb = m0 + wr * 128 + mi * 16 + fq * 4;
#pragma unroll
                for (int r = 0; r < 4; r++)
                    Out[(size_t)(mb + r) * 2048 + n] = acc[mi][nj][r];
            }
        }
    }
}

// ---------------------------------------------------------------------------
// Router, 8 rows/block: sum split-K partials + bias -> amp -> logits (gate &
// noise matvecs with all 256 threads) -> top-3 -> softmax -> scatter.
// ---------------------------------------------------------------------------
__global__ __launch_bounds__(256) void router_kernel(
    const float* __restrict__ P01, const float* __restrict__ P23, int ZK,
    const float* __restrict__ b2,
    const float* __restrict__ w_gate, const float* __restrict__ w_noise,
    const float* __restrict__ noise_z, float* __restrict__ gates)
{
    __shared__ float s_amp[8][1024];
    __shared__ float s_dot[8][176];
    __shared__ float s_lg[8][88];
    __shared__ int   s_idx[8][3];
    __shared__ float s_val[8][3];

    const int tid = threadIdx.x;
    const int r0 = blockIdx.x * 8;
    const size_t PSZ = (size_t)2048 * 2048;

    // amp
    for (int idx = tid; idx < 8 * 1024; idx += 256) {
        int row = idx >> 10, i = idx & 1023;
        size_t roff = (size_t)(r0 + row) * 2048;
        float orr = b2[i];
        float oii = b2[1024 + i];
        for (int zz = 0; zz < ZK; zz++) {
            const float* Pz = ((zz < 2) ? (P01 + (size_t)zz * PSZ)
                                        : (P23 + (size_t)(zz - 2) * PSZ)) + roff;
            orr += Pz[i];
            oii += Pz[1024 + i];
        }
        s_amp[row][i] = sqrtf(orr * orr + oii * oii);
    }
    __syncthreads();

    // dots: 8 rows x 176 cols (gate 0..87, noise 88..175), K=1024, float4 amp
    for (int idx = tid; idx < 8 * 176; idx += 256) {
        int row = idx / 176, c = idx % 176;
        const float* wcol = (c < 88) ? (w_gate + c) : (w_noise + (c - 88));
        float s = 0.f;
        const float4* av = (const float4*)s_amp[row];
        for (int k4 = 0; k4 < 256; k4++) {
            float4 a = av[k4];
            int k = k4 * 4;
            s = fmaf(a.x, wcol[(size_t)(k + 0) * 88], s);
            s = fmaf(a.y, wcol[(size_t)(k + 1) * 88], s);
            s = fmaf(a.z, wcol[(size_t)(k + 2) * 88], s);
            s = fmaf(a.w, wcol[(size_t)(k + 3) * 88], s);
        }
        s_dot[row][c] = s;
    }
    __syncthreads();

    // logits
    for (int idx = tid; idx < 8 * 88; idx += 256) {
        int row = idx / 88, c = idx % 88;
        float cn = s_dot[row][88 + c];
        float ns = (cn > 20.f) ? cn : log1pf(expf(cn));
        ns += 0.01f;
        s_lg[row][c] = s_dot[row][c] + noise_z[(size_t)(r0 + row) * 88 + c] * ns;
    }
    __syncthreads();

    // top-3 per row (threads 0..7)
    if (tid < 8) {
        int i0 = -1, i1 = -1, i2 = -1;
        float v0 = -1e30f, v1 = -1e30f, v2 = -1e30f;
        for (int i = 0; i < P_DIM; i++) {
            float t = s_lg[tid][i];
            if (t > v0) { v0 = t; i0 = i; }
        }
        for (int i = 0; i < P_DIM; i++) {
            if (i == i0) continue;
            float t = s_lg[tid][i];
            if (t > v1) { v1 = t; i1 = i; }
        }
        for (int i = 0; i < P_DIM; i++) {
            if (i == i0 || i == i1) continue;
            float t = s_lg[tid][i];
            if (t > v2) { v2 = t; i2 = i; }
        }
        s_idx[tid][0] = i0; s_idx[tid][1] = i1; s_idx[tid][2] = i2;
        s_val[tid][0] = v0; s_val[tid][1] = v1; s_val[tid][2] = v2;
    }
    __syncthreads();

    // gates
    for (int idx = tid; idx < 8 * 88; idx += 256) {
        int row = idx / 88, c = idx % 88;
        float m = s_val[row][0];
        float e0 = expf(s_val[row][0] - m);
        float e1 = expf(s_val[row][1] - m);
        float e2 = expf(s_val[row][2] - m);
        float inv = 1.f / (e0 + e1 + e2);
        float g = 0.f;
        if (c == s_idx[row][0]) g = e0 * inv;
        else if (c == s_idx[row][1]) g = e1 * inv;
        else if (c == s_idx[row][2]) g = e2 * inv;
        gates[(size_t)(r0 + row) * 88 + c] = g;
    }
}

// ---------------------------------------------------------------------------
extern "C" void kernel_launch(void* const* d_in, const int* in_sizes, int n_in,
                              void* d_out, int out_size, void* d_ws, size_t ws_size,
                              hipStream_t stream)
{
    const float* x       = (const float*)d_in[0];
    const float* w_start = (const float*)d_in[1];
    const float* b_start = (const float*)d_in[2];
    const float* w1      = (const float*)d_in[3];
    const float* b1      = (const float*)d_in[4];
    const float* w2      = (const float*)d_in[5];
    const float* b2      = (const float*)d_in[6];
    const float* w_gate  = (const float*)d_in[7];
    const float* w_noise = (const float*)d_in[8];
    const float* noise_z = (const float*)d_in[9];
    float* gates = (float*)d_out;

    const size_t MB = 1024 * 1024;
    char* base = (char*)d_ws;
    u16*  A1   = (u16*)(base + 16 * MB);     // [16,32) — dead after gemm1
    u16*  BT   = (u16*)(base + 32 * MB);     // [32,96) — BTk1 then BTk2
    u16*  A2   = (u16*)(base + 96 * MB);     // [96,160)
    float* P01 = (float*)base;               // partials z0,z1 -> [0,32)
    float* P23 = (float*)(base + 160 * MB);  // partials z2,z3 -> [160,192)

    int ZK = (ws_size >= (size_t)192 * MB) ? 4 : 2;

    hipFuncSetAttribute(reinterpret_cast<const void*>(&gemm8p<0, 1>),
                        hipFuncAttributeMaxDynamicSharedMemorySize, 65536);
    hipFuncSetAttribute(reinterpret_cast<const void*>(&gemm8p<1, 2>),
                        hipFuncAttributeMaxDynamicSharedMemorySize, 65536);

    fft_kernel<<<B_DIM / 2, 256, 0, stream>>>(x, w_start, b_start, A1);

    // layer 1: M=2048, N=8192, Kc=1024 (K_eff=6144 -> 192 K32-tiles); XCD swizzle
    conv_bt_kernel<<<dim3(F_DIM / 32, H_DIM / 32), dim3(32, 8), 0, stream>>>(
        w1, BT, F_DIM, H_DIM);
    gemm8p<0, 1><<<256, 512, 65536, stream>>>(
        A1, BT, b1, b1 + H_DIM, A2, nullptr, nullptr, F_DIM, 10, H_DIM, 192);

    // layer 2: M=2048, N=2048, Kc=4096 (K_eff=24576 -> 768 K32-tiles), split-K;
    // 1-D grid with XCD-pinned A-panels (SWZ=2)
    conv_bt_kernel<<<dim3(H_DIM / 32, F_DIM / 32), dim3(32, 8), 0, stream>>>(
        w2, BT, H_DIM, F_DIM);
    gemm8p<1, 2><<<64 * ZK, 512, 65536, stream>>>(
        A2, BT, nullptr, nullptr, nullptr, P01, P23, H_DIM, 12, F_DIM, 768 / ZK);

    router_kernel<<<B_DIM / 8, 256, 0, stream>>>(
        P01, P23, ZK, b2, w_gate, w_noise, noise_z, gates);
}

// Round 11
// 583.525 us; speedup vs baseline: 1.1151x; 1.1151x over previous
//
#include <hip/hip_runtime.h>
#include <hip/hip_bf16.h>
#include <math.h>

#define B_DIM 2048
#define L_DIM 2048
#define F_DIM 1024
#define H_DIM 4096
#define P_DIM 88

typedef unsigned short u16;
typedef short bf16x8 __attribute__((ext_vector_type(8)));
typedef float f32x4 __attribute__((ext_vector_type(4)));

// ---- bf16 split helpers (RNE) ----
__device__ __forceinline__ u16 f2bf(float x) {
    unsigned u = __float_as_uint(x);
    return (u16)((u + 0x7fffu + ((u >> 16) & 1u)) >> 16);
}
__device__ __forceinline__ float bf2f(u16 h) {
    return __uint_as_float(((unsigned)h) << 16);
}

// ---- async global->LDS, 16B per lane (dest = wave-uniform base + lane*16) ----
__device__ __forceinline__ void gload_lds16(const void* g, void* l) {
    unsigned loff = (unsigned)(uintptr_t)l;
    __builtin_amdgcn_global_load_lds(
        reinterpret_cast<const __attribute__((address_space(1))) void*>(
            reinterpret_cast<uintptr_t>(g)),
        reinterpret_cast<__attribute__((address_space(3))) void*>(loff),
        16, 0, 0);
}

// ---------------------------------------------------------------------------
// Fused prep: blocks [0,1024) = start_fc + real-pair FFT (rows 2b,2b+1 as
// re+im of one complex 2048-FFT, conjugate-symmetry unpack) -> A1
// [rh | rl | ih | il]; blocks [1024,1024+4096) = conv of w1 -> BT1
// [2Nh][4Kc] transposed split layout (independent of FFT part).
// ---------------------------------------------------------------------------
__global__ __launch_bounds__(256) void prep_kernel(
    const float* __restrict__ x, const float* __restrict__ w_start,
    const float* __restrict__ b_start, u16* __restrict__ A1,
    const float* __restrict__ w1, u16* __restrict__ BT1)
{
    __shared__ float re[2048];
    __shared__ float im[2048];
    __shared__ float twr[1024];
    __shared__ float twi[1024];
    __shared__ float t0s[32][33];
    __shared__ float t1s[32][33];

    const int tid = threadIdx.x;

    if (blockIdx.x < 1024) {
        // ================= FFT part =================
        int b = blockIdx.x;                       // pair index 0..1023
        const size_t row0 = (size_t)(2 * b) * 2048;

        const float4* wp = (const float4*)w_start;
        float4 w0 = wp[0], w1v = wp[1], w2 = wp[2], w3 = wp[3];
        float bs = b_start[0];

        for (int i = tid; i < 1024; i += 256) {
            float ang = -6.283185307179586f * ((float)i / 2048.0f);
            sincosf(ang, &twi[i], &twr[i]);
        }

        for (int l = tid; l < 2048; l += 256) {
            const float4* xp0 = (const float4*)(x + (row0 + l) * 16);
            const float4* xp1 = (const float4*)(x + (row0 + 2048 + l) * 16);
            float4 a0 = xp0[0], a1 = xp0[1], a2 = xp0[2], a3 = xp0[3];
            float4 c0 = xp1[0], c1 = xp1[1], c2 = xp1[2], c3 = xp1[3];
            float va = bs, vb = bs;
            va += a0.x * w0.x + a0.y * w0.y + a0.z * w0.z + a0.w * w0.w;
            va += a1.x * w1v.x + a1.y * w1v.y + a1.z * w1v.z + a1.w * w1v.w;
            va += a2.x * w2.x + a2.y * w2.y + a2.z * w2.z + a2.w * w2.w;
            va += a3.x * w3.x + a3.y * w3.y + a3.z * w3.z + a3.w * w3.w;
            vb += c0.x * w0.x + c0.y * w0.y + c0.z * w0.z + c0.w * w0.w;
            vb += c1.x * w1v.x + c1.y * w1v.y + c1.z * w1v.z + c1.w * w1v.w;
            vb += c2.x * w2.x + c2.y * w2.y + c2.z * w2.z + c2.w * w2.w;
            vb += c3.x * w3.x + c3.y * w3.y + c3.z * w3.z + c3.w * w3.w;
            unsigned j = __brev((unsigned)l) >> 21;   // bit-reversed position
            re[j] = va;
            im[j] = vb;
        }
        __syncthreads();

        for (int s = 1; s <= 11; s++) {
            int half = 1 << (s - 1);
            for (int t = tid; t < 1024; t += 256) {
                int j = t & (half - 1);
                int base = (t >> (s - 1)) << s;
                int idx = j << (11 - s);
                float wr = twr[idx], wi = twi[idx];
                int i0 = base + j, i1 = i0 + half;
                float br = re[i1], bi = im[i1];
                float tr = br * wr - bi * wi;
                float ti = br * wi + bi * wr;
                float ar = re[i0], ai = im[i0];
                re[i0] = ar + tr; im[i0] = ai + ti;
                re[i1] = ar - tr; im[i1] = ai - ti;
            }
            __syncthreads();
        }

        const float sc = 0.5f * 0.022097086912079612f;  // 0.5 / sqrt(2048)
        u16* r0 = A1 + (size_t)(2 * b) * 4096;
        u16* r1 = r0 + 4096;
        for (int t = tid; t < 1024; t += 256) {
            int k = t + 1;
            int nk = 2048 - k;
            float Zr = re[k], Zi = im[k], Yr = re[nk], Yi = im[nk];
            float Ar = (Zr + Yr) * sc;
            float Ai = (Zi - Yi) * sc;
            float Br = (Zi + Yi) * sc;
            float Bi = (Yr - Zr) * sc;
            u16 h, lo;
            h = f2bf(Ar); lo = f2bf(Ar - bf2f(h)); r0[t] = h; r0[1024 + t] = lo;
            h = f2bf(Ai); lo = f2bf(Ai - bf2f(h)); r0[2048 + t] = h; r0[3072 + t] = lo;
            h = f2bf(Br); lo = f2bf(Br - bf2f(h)); r1[t] = h; r1[1024 + t] = lo;
            h = f2bf(Bi); lo = f2bf(Bi - bf2f(h)); r1[2048 + t] = h; r1[3072 + t] = lo;
        }
    } else {
        // ================= conv1 part (w1 -> BT1) =================
        const int Kc = F_DIM, Nh = H_DIM;
        int bid = blockIdx.x - 1024;
        int k0 = (bid & 31) * 32;                // 32 k-blocks
        int n0 = (bid >> 5) * 32;                // 128 n-blocks
        int tx = tid & 31, ty = tid >> 5;        // (32, 8)
        const float* w0 = w1;
        const float* w1b = w1 + (size_t)Kc * Nh;

#pragma unroll
        for (int i = 0; i < 4; i++) {
            int k = k0 + ty + 8 * i;
            t0s[ty + 8 * i][tx] = w0[(size_t)k * Nh + n0 + tx];
            t1s[ty + 8 * i][tx] = w1b[(size_t)k * Nh + n0 + tx];
        }
        __syncthreads();

        size_t K4 = 4 * (size_t)Kc;
        int k = k0 + tx;
#pragma unroll
        for (int i = 0; i < 4; i++) {
            int nl = ty + 8 * i;
            int n = n0 + nl;
            float br = t0s[tx][nl];
            float bi = t1s[tx][nl];
            u16 brh = f2bf(br); u16 brl = f2bf(br - bf2f(brh));
            float nbi = -bi;
            u16 nih = f2bf(nbi); u16 nil = f2bf(nbi - bf2f(nih));
            u16 pih = f2bf(bi);  u16 pil = f2bf(bi - bf2f(pih));
            u16* rowr = BT1 + (size_t)n * K4;
            rowr[0 * Kc + k] = brh; rowr[1 * Kc + k] = brl;
            rowr[2 * Kc + k] = nih; rowr[3 * Kc + k] = nil;
            u16* rowi = BT1 + (size_t)(Nh + n) * K4;
            rowi[0 * Kc + k] = pih; rowi[1 * Kc + k] = pil;
            rowi[2 * Kc + k] = brh; rowi[3 * Kc + k] = brl;
        }
    }
}

// ---------------------------------------------------------------------------
// Weight conversion w[2][Kc][Nh] fp32 -> BT [2*Nh][4*Kc] bf16 (transposed,
// split) — standalone, used for w2 after gemm1 frees the BT region.
// ---------------------------------------------------------------------------
__global__ __launch_bounds__(256) void conv_bt_kernel(
    const float* __restrict__ w, u16* __restrict__ BT, int Kc, int Nh)
{
    __shared__ float t0[32][33];
    __shared__ float t1[32][33];
    int k0 = blockIdx.x * 32, n0 = blockIdx.y * 32;
    int tx = threadIdx.x, ty = threadIdx.y;     // (32, 8)
    const float* w0 = w;
    const float* w1 = w + (size_t)Kc * Nh;

#pragma unroll
    for (int i = 0; i < 4; i++) {
        int k = k0 + ty + 8 * i;
        t0[ty + 8 * i][tx] = w0[(size_t)k * Nh + n0 + tx];
        t1[ty + 8 * i][tx] = w1[(size_t)k * Nh + n0 + tx];
    }
    __syncthreads();

    size_t K4 = 4 * (size_t)Kc;
    int k = k0 + tx;
#pragma unroll
    for (int i = 0; i < 4; i++) {
        int nl = ty + 8 * i;
        int n = n0 + nl;
        float br = t0[tx][nl];
        float bi = t1[tx][nl];
        u16 brh = f2bf(br); u16 brl = f2bf(br - bf2f(brh));
        float nbi = -bi;
        u16 nih = f2bf(nbi); u16 nil = f2bf(nbi - bf2f(nih));
        u16 pih = f2bf(bi);  u16 pil = f2bf(bi - bf2f(pih));
        u16* rowr = BT + (size_t)n * K4;
        rowr[0 * Kc + k] = brh; rowr[1 * Kc + k] = brl;
        rowr[2 * Kc + k] = nih; rowr[3 * Kc + k] = nil;
        u16* rowi = BT + (size_t)(Nh + n) * K4;
        rowi[0 * Kc + k] = pih; rowi[1 * Kc + k] = pil;
        rowi[2 * Kc + k] = brh; rowi[3 * Kc + k] = brl;
    }
}

// ---------------------------------------------------------------------------
// Deep-pipelined split-bf16 GEMM (R6/R9 structure — measured best: 45.5%
// MfmaUtil, 0 bank conflicts). 256x256 tile, BK=32, 8 waves (2M x 4N),
// ring of 4 LDS slots per operand.
// Per tile t:
//   stage(t+2); read ph2-A frags (slot t);      MFMA ph1 (a,b from last iter)
//   vmcnt(4 | 0 if no stage); s_barrier
//   read next-tile ph1-A frags (slot t+1);      MFMA ph2 (c,b)
//   read next-tile B frags (slot t+1)           [b regs free after ph2]
// SWZ=1: XCD-chunked grid for layer 1 (256 blocks).
// SWZ=2: layer-2 locality grid: by = bid&7 (XCD-pinned A-panel),
//        bx = (bid>>3)&7, z = bid>>6  (bijective for 64*ZK blocks).
// ---------------------------------------------------------------------------
extern __shared__ char smem8p[];

#define MFMA16(ACC0, ACC1, ACC2, ACC3, A0, A1, A2, A3, B0, B1, B2, B3)           \
    ACC0[0] = __builtin_amdgcn_mfma_f32_16x16x32_bf16(A0, B0, ACC0[0], 0, 0, 0); \
    ACC0[1] = __builtin_amdgcn_mfma_f32_16x16x32_bf16(A0, B1, ACC0[1], 0, 0, 0); \
    ACC0[2] = __builtin_amdgcn_mfma_f32_16x16x32_bf16(A0, B2, ACC0[2], 0, 0, 0); \
    ACC0[3] = __builtin_amdgcn_mfma_f32_16x16x32_bf16(A0, B3, ACC0[3], 0, 0, 0); \
    ACC1[0] = __builtin_amdgcn_mfma_f32_16x16x32_bf16(A1, B0, ACC1[0], 0, 0, 0); \
    ACC1[1] = __builtin_amdgcn_mfma_f32_16x16x32_bf16(A1, B1, ACC1[1], 0, 0, 0); \
    ACC1[2] = __builtin_amdgcn_mfma_f32_16x16x32_bf16(A1, B2, ACC1[2], 0, 0, 0); \
    ACC1[3] = __builtin_amdgcn_mfma_f32_16x16x32_bf16(A1, B3, ACC1[3], 0, 0, 0); \
    ACC2[0] = __builtin_amdgcn_mfma_f32_16x16x32_bf16(A2, B0, ACC2[0], 0, 0, 0); \
    ACC2[1] = __builtin_amdgcn_mfma_f32_16x16x32_bf16(A2, B1, ACC2[1], 0, 0, 0); \
    ACC2[2] = __builtin_amdgcn_mfma_f32_16x16x32_bf16(A2, B2, ACC2[2], 0, 0, 0); \
    ACC2[3] = __builtin_amdgcn_mfma_f32_16x16x32_bf16(A2, B3, ACC2[3], 0, 0, 0); \
    ACC3[0] = __builtin_amdgcn_mfma_f32_16x16x32_bf16(A3, B0, ACC3[0], 0, 0, 0); \
    ACC3[1] = __builtin_amdgcn_mfma_f32_16x16x32_bf16(A3, B1, ACC3[1], 0, 0, 0); \
    ACC3[2] = __builtin_amdgcn_mfma_f32_16x16x32_bf16(A3, B2, ACC3[2], 0, 0, 0); \
    ACC3[3] = __builtin_amdgcn_mfma_f32_16x16x32_bf16(A3, B3, ACC3[3], 0, 0, 0);

template <int EPI, int SWZ>
__global__ __launch_bounds__(512, 2) void gemm8p(
    const u16* __restrict__ A, const u16* __restrict__ B,
    const float* __restrict__ biasL, const float* __restrict__ biasR,
    u16* __restrict__ OutU, float* __restrict__ P01, float* __restrict__ P23,
    int Kc, int KcLog, int NH, int nt)
{
    char* ldsA = smem8p;              // 4 slots x 16384 B  (A tile 256x32 bf16)
    char* ldsB = smem8p + 65536;      // 4 slots x 16384 B

    const int tid = threadIdx.x;
    const int w = tid >> 6, lane = tid & 63;
    const int wr = w >> 2, wc = w & 3;           // 2M x 4N waves
    const int fr = lane & 15, kb = lane >> 4;

    int bx, by, z;
    if (SWZ == 1) {
        int b = blockIdx.x;
        int xcd = b & 7, idx = b >> 3;
        bx = 4 * xcd + (idx & 3);                // 32 N-blocks
        by = idx >> 2;                           // 8 M-blocks
        z = 0;
    } else if (SWZ == 2) {
        int b = blockIdx.x;                      // 64*ZK blocks, 1-D
        by = b & 7;                              // XCD-pinned A-panel
        int s = b >> 3;
        bx = s & 7;
        z = s >> 3;
    } else {
        bx = blockIdx.x; by = blockIdx.y; z = blockIdx.z;
    }
    const int n0 = bx * 256, m0 = by * 256;
    const size_t K4 = 4 * (size_t)Kc;

    // staging: thread covers one 16B chunk per issue; 2 issues each for A,B
    const int srow = tid >> 2;
    const int lk8 = (((tid & 3) ^ ((tid >> 3) & 3))) * 8;   // src elem offset
    const int wb = (tid >> 6) * 1024;                       // wave dest base (B)

    // frag read lane offset (bytes): row fr, chunk kb ^ ((fr>>1)&3)
    const int laneOff = fr * 64 + ((kb ^ ((fr >> 1) & 3)) << 4);

    f32x4 acc[8][4];
#pragma unroll
    for (int i = 0; i < 8; i++)
#pragma unroll
        for (int j = 0; j < 4; j++)
            acc[i][j] = (f32x4){0.f, 0.f, 0.f, 0.f};

    const int t0 = z * nt, te = t0 + nt;

    auto colA = [&](int t) {
        int k0 = t << 5;
        int seg = k0 >> KcLog, kk = k0 & (Kc - 1);
        int r3 = seg >= 3 ? seg - 3 : seg;
        int bs = seg >= 3 ? 2 : 0;
        return (bs + (r3 == 1 ? 1 : 0)) * Kc + kk;
    };
    auto colB = [&](int t) {
        int k0 = t << 5;
        int seg = k0 >> KcLog, kk = k0 & (Kc - 1);
        int r3 = seg >= 3 ? seg - 3 : seg;
        int bs = seg >= 3 ? 2 : 0;
        return (bs + (r3 == 2 ? 1 : 0)) * Kc + kk;
    };
    auto stageA = [&](int t) {
        const u16* src = A + (size_t)(m0 + srow) * K4 + colA(t) + lk8;
        char* dst = ldsA + (t & 3) * 16384 + wb;
        gload_lds16(src, dst);
        gload_lds16(src + (size_t)128 * K4, dst + 8192);
    };
    auto stageB = [&](int t) {
        const u16* src = B + (size_t)(n0 + srow) * K4 + colB(t) + lk8;
        char* dst = ldsB + (t & 3) * 16384 + wb;
        gload_lds16(src, dst);
        gload_lds16(src + (size_t)128 * K4, dst + 8192);
    };
    auto aBase = [&](int t) -> const char* {
        return ldsA + (t & 3) * 16384 + wr * 8192 + laneOff;
    };
    auto bBase = [&](int t) -> const char* {
        return ldsB + (t & 3) * 16384 + wc * 4096 + laneOff;
    };

    // prologue: stage t0, t0+1; confirm t0; read its phase-1 frags
    stageA(t0); stageB(t0);
    if (t0 + 1 < te) { stageA(t0 + 1); stageB(t0 + 1); }
    if (t0 + 1 < te) asm volatile("s_waitcnt vmcnt(4)" ::: "memory");
    else             asm volatile("s_waitcnt vmcnt(0)" ::: "memory");
    asm volatile("s_barrier" ::: "memory");

    bf16x8 b0, b1, b2, b3, a0, a1, a2, a3;
    {
        const char* aS = aBase(t0);
        const char* bS = bBase(t0);
        b0 = *(const bf16x8*)(bS + 0 * 1024);
        b1 = *(const bf16x8*)(bS + 1 * 1024);
        b2 = *(const bf16x8*)(bS + 2 * 1024);
        b3 = *(const bf16x8*)(bS + 3 * 1024);
        a0 = *(const bf16x8*)(aS + 0 * 1024);
        a1 = *(const bf16x8*)(aS + 1 * 1024);
        a2 = *(const bf16x8*)(aS + 2 * 1024);
        a3 = *(const bf16x8*)(aS + 3 * 1024);
    }

    for (int t = t0; t < te; ++t) {
        const bool haveStage = (t + 2 < te);
        const bool haveNext  = (t + 1 < te);

        // issue next-next tile's stages (loads span the whole tile)
        if (haveStage) { stageA(t + 2); stageB(t + 2); }

        // pre-read phase-2 A-frags (slot t, published) -- covered by MFMA ph1
        const char* aS = aBase(t);
        bf16x8 c0 = *(const bf16x8*)(aS + 4096 + 0 * 1024);
        bf16x8 c1 = *(const bf16x8*)(aS + 4096 + 1 * 1024);
        bf16x8 c2 = *(const bf16x8*)(aS + 4096 + 2 * 1024);
        bf16x8 c3 = *(const bf16x8*)(aS + 4096 + 3 * 1024);

        // ---- phase 1: M-half 0 ----
        __builtin_amdgcn_s_setprio(1);
        MFMA16(acc[0], acc[1], acc[2], acc[3], a0, a1, a2, a3, b0, b1, b2, b3)
        __builtin_amdgcn_s_setprio(0);

        // confirm tile t+1's 4 loads; keep t+2's 4 in flight (if staged)
        if (haveStage) asm volatile("s_waitcnt vmcnt(4)" ::: "memory");
        else           asm volatile("s_waitcnt vmcnt(0)" ::: "memory");
        asm volatile("s_barrier" ::: "memory");

        // pre-read next tile's phase-1 A-frags (a regs free after ph1)
        if (haveNext) {
            const char* aN = aBase(t + 1);
            a0 = *(const bf16x8*)(aN + 0 * 1024);
            a1 = *(const bf16x8*)(aN + 1 * 1024);
            a2 = *(const bf16x8*)(aN + 2 * 1024);
            a3 = *(const bf16x8*)(aN + 3 * 1024);
        }

        // ---- phase 2: M-half 1 ----
        __builtin_amdgcn_s_setprio(1);
        MFMA16(acc[4], acc[5], acc[6], acc[7], c0, c1, c2, c3, b0, b1, b2, b3)
        __builtin_amdgcn_s_setprio(0);

        // pre-read next tile's B-frags (b regs free after ph2)
        if (haveNext) {
            const char* bN = bBase(t + 1);
            b0 = *(const bf16x8*)(bN + 0 * 1024);
            b1 = *(const bf16x8*)(bN + 1 * 1024);
            b2 = *(const bf16x8*)(bN + 2 * 1024);
            b3 = *(const bf16x8*)(bN + 3 * 1024);
        }
    }

    // ---- epilogue ----
    const int fq = kb;
#pragma unroll
    for (int nj = 0; nj < 4; nj++) {
        int n = n0 + wc * 64 + nj * 16 + fr;
        if (EPI == 0) {
            bool left = (n < NH);
            int nn = left ? n : (n - NH);
            float bias = left ? biasL[n] : biasR[nn];
#pragma unroll
            for (int mi = 0; mi < 8; mi++) {
                int mb = m0 + wr * 128 + mi * 16 + fq * 4;
#pragma unroll
                for (int r = 0; r < 4; r++) {
                    float val = fmaxf(acc[mi][nj][r] + bias, 0.f);
                    u16 h = f2bf(val);
                    u16 lo = f2bf(val - bf2f(h));
                    size_t rb = (size_t)(mb + r) * (4 * (size_t)NH);
                    if (left) { OutU[rb + nn] = h; OutU[rb + NH + nn] = lo; }
                    else { OutU[rb + 2 * (size_t)NH + nn] = h; OutU[rb + 3 * (size_t)NH + nn] = lo; }
                }
            }
        } else {
            const size_t PSZ = (size_t)2048 * 2048;
            float* Out = (z < 2) ? (P01 + (size_t)z * PSZ) : (P23 + (size_t)(z - 2) * PSZ);
#pragma unroll
            for (int mi = 0; mi < 8; mi++) {
                int mb = m0 + wr * 128 + mi * 16 + fq * 4;
#pragma unroll
                for (int r = 0; r < 4; r++)
                    Out[(size_t)(mb + r) * 2048 + n] = acc[mi][nj][r];
            }
        }
    }
}

// ---------------------------------------------------------------------------
// Router, 8 rows/block: sum split-K partials + bias -> amp -> logits (gate &
// noise matvecs with all 256 threads) -> top-3 -> softmax -> scatter.
// ---------------------------------------------------------------------------
__global__ __launch_bounds__(256) void router_kernel(
    const float* __restrict__ P01, const float* __restrict__ P23, int ZK,
    const float* __restrict__ b2,
    const float* __restrict__ w_gate, const float* __restrict__ w_noise,
    const float* __restrict__ noise_z, float* __restrict__ gates)
{
    __shared__ float s_amp[8][1024];
    __shared__ float s_dot[8][176];
    __shared__ float s_lg[8][88];
    __shared__ int   s_idx[8][3];
    __shared__ float s_val[8][3];

    const int tid = threadIdx.x;
    const int r0 = blockIdx.x * 8;
    const size_t PSZ = (size_t)2048 * 2048;

    // amp
    for (int idx = tid; idx < 8 * 1024; idx += 256) {
        int row = idx >> 10, i = idx & 1023;
        size_t roff = (size_t)(r0 + row) * 2048;
        float orr = b2[i];
        float oii = b2[1024 + i];
        for (int zz = 0; zz < ZK; zz++) {
            const float* Pz = ((zz < 2) ? (P01 + (size_t)zz * PSZ)
                                        : (P23 + (size_t)(zz - 2) * PSZ)) + roff;
            orr += Pz[i];
            oii += Pz[1024 + i];
        }
        s_amp[row][i] = sqrtf(orr * orr + oii * oii);
    }
    __syncthreads();

    // dots: 8 rows x 176 cols (gate 0..87, noise 88..175), K=1024, float4 amp
    for (int idx = tid; idx < 8 * 176; idx += 256) {
        int row = idx / 176, c = idx % 176;
        const float* wcol = (c < 88) ? (w_gate + c) : (w_noise + (c - 88));
        float s = 0.f;
        const float4* av = (const float4*)s_amp[row];
        for (int k4 = 0; k4 < 256; k4++) {
            float4 a = av[k4];
            int k = k4 * 4;
            s = fmaf(a.x, wcol[(size_t)(k + 0) * 88], s);
            s = fmaf(a.y, wcol[(size_t)(k + 1) * 88], s);
            s = fmaf(a.z, wcol[(size_t)(k + 2) * 88], s);
            s = fmaf(a.w, wcol[(size_t)(k + 3) * 88], s);
        }
        s_dot[row][c] = s;
    }
    __syncthreads();

    // logits
    for (int idx = tid; idx < 8 * 88; idx += 256) {
        int row = idx / 88, c = idx % 88;
        float cn = s_dot[row][88 + c];
        float ns = (cn > 20.f) ? cn : log1pf(expf(cn));
        ns += 0.01f;
        s_lg[row][c] = s_dot[row][c] + noise_z[(size_t)(r0 + row) * 88 + c] * ns;
    }
    __syncthreads();

    // top-3 per row (threads 0..7)
    if (tid < 8) {
        int i0 = -1, i1 = -1, i2 = -1;
        float v0 = -1e30f, v1 = -1e30f, v2 = -1e30f;
        for (int i = 0; i < P_DIM; i++) {
            float t = s_lg[tid][i];
            if (t > v0) { v0 = t; i0 = i; }
        }
        for (int i = 0; i < P_DIM; i++) {
            if (i == i0) continue;
            float t = s_lg[tid][i];
            if (t > v1) { v1 = t; i1 = i; }
        }
        for (int i = 0; i < P_DIM; i++) {
            if (i == i0 || i == i1) continue;
            float t = s_lg[tid][i];
            if (t > v2) { v2 = t; i2 = i; }
        }
        s_idx[tid][0] = i0; s_idx[tid][1] = i1; s_idx[tid][2] = i2;
        s_val[tid][0] = v0; s_val[tid][1] = v1; s_val[tid][2] = v2;
    }
    __syncthreads();

    // gates
    for (int idx = tid; idx < 8 * 88; idx += 256) {
        int row = idx / 88, c = idx % 88;
        float m = s_val[row][0];
        float e0 = expf(s_val[row][0] - m);
        float e1 = expf(s_val[row][1] - m);
        float e2 = expf(s_val[row][2] - m);
        float inv = 1.f / (e0 + e1 + e2);
        float g = 0.f;
        if (c == s_idx[row][0]) g = e0 * inv;
        else if (c == s_idx[row][1]) g = e1 * inv;
        else if (c == s_idx[row][2]) g = e2 * inv;
        gates[(size_t)(r0 + row) * 88 + c] = g;
    }
}

// ---------------------------------------------------------------------------
extern "C" void kernel_launch(void* const* d_in, const int* in_sizes, int n_in,
                              void* d_out, int out_size, void* d_ws, size_t ws_size,
                              hipStream_t stream)
{
    const float* x       = (const float*)d_in[0];
    const float* w_start = (const float*)d_in[1];
    const float* b_start = (const float*)d_in[2];
    const float* w1      = (const float*)d_in[3];
    const float* b1      = (const float*)d_in[4];
    const float* w2      = (const float*)d_in[5];
    const float* b2      = (const float*)d_in[6];
    const float* w_gate  = (const float*)d_in[7];
    const float* w_noise = (const float*)d_in[8];
    const float* noise_z = (const float*)d_in[9];
    float* gates = (float*)d_out;

    const size_t MB = 1024 * 1024;
    char* base = (char*)d_ws;
    u16*  A1   = (u16*)(base + 16 * MB);     // [16,32) — dead after gemm1
    u16*  BT   = (u16*)(base + 32 * MB);     // [32,96) — BT1 then BT2
    u16*  A2   = (u16*)(base + 96 * MB);     // [96,160)
    float* P01 = (float*)base;               // partials z0,z1 -> [0,32)
    float* P23 = (float*)(base + 160 * MB);  // partials z2,z3 -> [160,192)

    int ZK = (ws_size >= (size_t)192 * MB) ? 4 : 2;

    hipFuncSetAttribute(reinterpret_cast<const void*>(&gemm8p<0, 1>),
                        hipFuncAttributeMaxDynamicSharedMemorySize, 131072);
    hipFuncSetAttribute(reinterpret_cast<const void*>(&gemm8p<1, 2>),
                        hipFuncAttributeMaxDynamicSharedMemorySize, 131072);

    // fused: start_fc + FFT (1024 pair-blocks) and conv1 (4096 blocks)
    prep_kernel<<<1024 + 4096, 256, 0, stream>>>(
        x, w_start, b_start, A1, w1, BT);

    // layer 1: M=2048, N=8192, Kc=1024 (K_eff=6144 -> 192 K32-tiles); XCD swizzle
    gemm8p<0, 1><<<256, 512, 131072, stream>>>(
        A1, BT, b1, b1 + H_DIM, A2, nullptr, nullptr, F_DIM, 10, H_DIM, 192);

    // layer 2: M=2048, N=2048, Kc=4096 (K_eff=24576 -> 768 K32-tiles), split-K;
    // 1-D grid with XCD-pinned A-panels (SWZ=2)
    conv_bt_kernel<<<dim3(H_DIM / 32, F_DIM / 32), dim3(32, 8), 0, stream>>>(
        w2, BT, H_DIM, F_DIM);
    gemm8p<1, 2><<<64 * ZK, 512, 131072, stream>>>(
        A2, BT, nullptr, nullptr, nullptr, P01, P23, H_DIM, 12, F_DIM, 768 / ZK);

    router_kernel<<<B_DIM / 8, 256, 0, stream>>>(
        P01, P23, ZK, b2, w_gate, w_noise, noise_z, gates);
}